// Round 1
// baseline (133.904 us; speedup 1.0000x reference)
//
#include <hip/hip_runtime.h>

#define BLOCK 256
#define FT 2048           // output elements per block (final kernel) — R13: was 1024

static __device__ __forceinline__ float ldz(const float* __restrict__ p, int i, int n) {
    return (i >= 0 && i < n) ? p[i] : 0.f;
}

// Quad-filter taps, reversed/deinterleaved, sqrt2 folded into the highpass set.
struct QFilt {
    float b0e[5], b0o[5], a0e[5], a0o[5];
    float b1e[5], b1o[5], a1e[5], a1o[5];
};

static __device__ __forceinline__ QFilt load_qfilt(
    const float* __restrict__ g0a, const float* __restrict__ g0b,
    const float* __restrict__ g1a, const float* __restrict__ g1b) {
    const float S2 = 1.4142135623730951f;
    QFilt f;
#pragma unroll
    for (int i = 0; i < 5; ++i) {
        f.b0e[i] = g0b[8 - 2 * i]; f.b0o[i] = g0b[9 - 2 * i];
        f.a0e[i] = g0a[8 - 2 * i]; f.a0o[i] = g0a[9 - 2 * i];
        f.b1e[i] = S2 * g1b[8 - 2 * i]; f.b1o[i] = S2 * g1b[9 - 2 * i];
        f.a1e[i] = S2 * g1a[8 - 2 * i]; f.a1o[i] = S2 * g1a[9 - 2 * i];
    }
    return f;
}

// Quad out[4s..4s+3], lo window INTERLEAVED in LDS:
// lo_s[lobase+2i]=lo[2s-4+2i], lo_s[lobase+2i+1]=lo[2s-3+2i]; r/i stride-1.
static __device__ __forceinline__ float4 quad_i(
    const float* __restrict__ lo_s, int lobase,
    const float* __restrict__ r_s, const float* __restrict__ i_s, int ribase,
    const QFilt& f) {
    float y0 = 0.f, y1 = 0.f, y2 = 0.f, y3 = 0.f;
#pragma unroll
    for (int i = 0; i < 5; ++i) {
        float ve = lo_s[lobase + 2 * i], vo = lo_s[lobase + 2 * i + 1];
        float vr = r_s[ribase + i], vi = i_s[ribase + i];
        y0 = fmaf(ve, f.b0e[i], y0); y2 = fmaf(ve, f.b0o[i], y2);
        y1 = fmaf(vo, f.a0e[i], y1); y3 = fmaf(vo, f.a0o[i], y3);
        y0 = fmaf(vr, f.b1e[i], y0); y2 = fmaf(vr, f.b1o[i], y2);
        y1 = fmaf(vi, f.a1e[i], y1); y3 = fmaf(vi, f.a1o[i], y3);
    }
    return make_float4(y0, y1, y2, y3);
}

// Quad with lo window DEINTERLEAVED: Ae[base+i]=lo[2s-4+2i], Ao[base+i]=lo[2s-3+2i].
static __device__ __forceinline__ float4 quad_d(
    const float* __restrict__ Ae, const float* __restrict__ Ao, int base,
    const float* __restrict__ r_s, const float* __restrict__ i_s, int ribase,
    const QFilt& f) {
    float y0 = 0.f, y1 = 0.f, y2 = 0.f, y3 = 0.f;
#pragma unroll
    for (int i = 0; i < 5; ++i) {
        float ve = Ae[base + i], vo = Ao[base + i];
        float vr = r_s[ribase + i], vi = i_s[ribase + i];
        y0 = fmaf(ve, f.b0e[i], y0); y2 = fmaf(ve, f.b0o[i], y2);
        y1 = fmaf(vo, f.a0e[i], y1); y3 = fmaf(vo, f.a0o[i], y3);
        y0 = fmaf(vr, f.b1e[i], y0); y2 = fmaf(vr, f.b1o[i], y2);
        y1 = fmaf(vi, f.a1e[i], y1); y3 = fmaf(vi, f.a1o[i], y3);
    }
    return make_float4(y0, y1, y2, y3);
}

// TWO fused coarse levels (R11 structure, unchanged — measured near floor).
__global__ void __launch_bounds__(BLOCK) pair_lvl(
    const float* __restrict__ up,
    const float* __restrict__ ru, const float* __restrict__ iu,
    const float* __restrict__ rl, const float* __restrict__ il,
    float* __restrict__ out,
    const float* __restrict__ g0a, const float* __restrict__ g0b,
    const float* __restrict__ g1a, const float* __restrict__ g1b,
    int L)
{
    __shared__ __align__(16) float upw[272], ruw[140], iuw[140], rlw[264], ilw[264];
    __shared__ __align__(16) float Ae[260], Ao[260];
    int tid = threadIdx.x, bx = blockIdx.x, row = blockIdx.y;
    int lup = L >> 2, lu8 = L >> 3, lql = L >> 2;
    const float* uprow = up + (size_t)row * lup;
    const float* rurow = ru + (size_t)row * lu8;
    const float* iurow = iu + (size_t)row * lu8;
    const float* rlrow = rl + (size_t)row * lql;
    const float* ilrow = il + (size_t)row * lql;
    bool bnd = (bx == 0) || (bx == (int)gridDim.x - 1);
    int S = bx << 8;
    int sAu = (S >> 1) - 1;
    int gu = S - 8;
    int gru = (S >> 1) - 4;
    int grl = S - 4;

    for (int i = tid; i < 270; i += BLOCK) {
        const float* src; float* dst; int k, gb, len;
        if (i < 68)       { src = uprow; dst = upw; k = i;       gb = gu + 4 * k;  len = lup; }
        else if (i < 103) { src = rurow; dst = ruw; k = i - 68;  gb = gru + 4 * k; len = lu8; }
        else if (i < 138) { src = iurow; dst = iuw; k = i - 103; gb = gru + 4 * k; len = lu8; }
        else if (i < 204) { src = rlrow; dst = rlw; k = i - 138; gb = grl + 4 * k; len = lql; }
        else              { src = ilrow; dst = ilw; k = i - 204; gb = grl + 4 * k; len = lql; }
        float4 v;
        if (!bnd) v = *reinterpret_cast<const float4*>(src + gb);
        else { v.x = ldz(src, gb, len); v.y = ldz(src, gb + 1, len);
               v.z = ldz(src, gb + 2, len); v.w = ldz(src, gb + 3, len); }
        *reinterpret_cast<float4*>(dst + 4 * k) = v;
    }
    __syncthreads();

    QFilt f = load_qfilt(g0a, g0b, g1a, g1b);
    if (tid < 130) {
        float4 q = quad_i(upw, 2 * tid + 2, ruw, iuw, tid + 1, f);
        if (bnd) {
            int sp = sAu + tid;
            if (sp < 0 || sp >= lu8) q = make_float4(0.f, 0.f, 0.f, 0.f);
        }
        Ae[2 * tid] = q.x; Ae[2 * tid + 1] = q.z;
        Ao[2 * tid] = q.y; Ao[2 * tid + 1] = q.w;
    }
    __syncthreads();

    float4 res = quad_d(Ae, Ao, tid, rlw, ilw, tid + 2, f);
    reinterpret_cast<float4*>(out + (size_t)row * L)[S + tid] = res;
}

// Fused last two levels. R13 change vs R12: 8 outputs/thread (FT 1024->2048).
// Rationale: counters showed neither HBM (49% achievable) nor VALU (39%) bound;
// waves stalled ~60% of residency on correlated barrier/vmcnt waits. Doubling
// per-thread work amortizes stage index math, both barriers, and filter loads,
// and keeps BOTH own x1 quads in registers (w[0..7] free). Neighbor quads come
// from deinterleaved x1qE/x1qO (stride-16 consecutive reads, conflict-free).
__global__ void __launch_bounds__(BLOCK) final_lvl(
    const float* __restrict__ x2,                                 // T/2 per row
    const float* __restrict__ r1, const float* __restrict__ i1,   // T/4 per row
    const float* __restrict__ r0, const float* __restrict__ i0,   // T/2 per row
    float* __restrict__ out,                                      // T per row
    const float* __restrict__ g0a, const float* __restrict__ g0b,
    const float* __restrict__ g1a, const float* __restrict__ g1b,
    const float* __restrict__ g0o, const float* __restrict__ g1o,
    int T_)
{
    const float S2 = 1.4142135623730951f;
    __shared__ __align__(16) float lo_s[1040], r1_s[520], i1_s[520];
    __shared__ __align__(16) float4 x1qE[257], x1qO[257];  // even/odd x1 quads
    const int X2_F4 = 260, R1_F4 = 130;
    const int TOT = X2_F4 + 2 * R1_F4;  // 520
    int row = blockIdx.y, tid = threadIdx.x;
    int n0 = blockIdx.x * FT;
    int t2 = T_ >> 1, t4 = T_ >> 2;
    int s0 = n0 >> 2, h0 = n0 >> 1;
    const float* lorow = x2 + (size_t)row * t2;
    const float* r1row = r1 + (size_t)row * t4;
    const float* i1row = i1 + (size_t)row * t4;
    const float* r0row = r0 + (size_t)row * t2;
    const float* i0row = i0 + (size_t)row * t2;
    bool bnd = (blockIdx.x == 0) || ((int)blockIdx.x == (int)gridDim.x - 1);

    // ---- hoisted epilogue loads: rA[e] = r0[h0 + 4*tid - 1 + e], e=0..5 ----
    // (issued at entry so ~900cy HBM latency overlaps stage + barrier + phase A)
    float rA[6], iA[6];
    {
        int u0 = h0 + 4 * tid - 1;
        if (!bnd) {
            float4 va = *reinterpret_cast<const float4*>(r0row + u0);
            float2 va2 = *reinterpret_cast<const float2*>(r0row + u0 + 4);
            float4 vb = *reinterpret_cast<const float4*>(i0row + u0);
            float2 vb2 = *reinterpret_cast<const float2*>(i0row + u0 + 4);
            rA[0] = va.x; rA[1] = va.y; rA[2] = va.z; rA[3] = va.w;
            rA[4] = va2.x; rA[5] = va2.y;
            iA[0] = vb.x; iA[1] = vb.y; iA[2] = vb.z; iA[3] = vb.w;
            iA[4] = vb2.x; iA[5] = vb2.y;
        } else {
#pragma unroll
            for (int e = 0; e < 6; ++e) {
                rA[e] = ldz(r0row, u0 + e, t2);
                iA[e] = ldz(i0row, u0 + e, t2);
            }
        }
    }
    float g0r[7], g1r[5];
#pragma unroll
    for (int j = 0; j < 7; ++j) g0r[j] = g0o[j];
#pragma unroll
    for (int j = 0; j < 5; ++j) g1r[j] = S2 * g1o[j];

    // stage: lo_s[g] = x2[2*s0-8+g] (g<1040); r1_s[g] = r1[s0-4+g] (g<520); i1_s likewise
    for (int i = tid; i < TOT; i += BLOCK) {
        const float* src; float* dst; int k, gb, len;
        if (i < X2_F4)             { src = lorow; dst = lo_s; k = i;               gb = 2 * s0 - 8 + 4 * k; len = t2; }
        else if (i < X2_F4 + R1_F4){ src = r1row; dst = r1_s; k = i - X2_F4;       gb = s0 - 4 + 4 * k;     len = t4; }
        else                       { src = i1row; dst = i1_s; k = i - X2_F4 - R1_F4; gb = s0 - 4 + 4 * k;   len = t4; }
        float4 v;
        if (!bnd) v = *reinterpret_cast<const float4*>(src + gb);
        else { v.x = ldz(src, gb, len); v.y = ldz(src, gb + 1, len);
               v.z = ldz(src, gb + 2, len); v.w = ldz(src, gb + 3, len); }
        *reinterpret_cast<float4*>(dst + 4 * k) = v;
    }
    __syncthreads();

    // phase A: x1 quads l=0..513; quad l = x1[4*(s0-1+l) .. +3].
    // thread t owns l=2t (->x1qE[t]) and l=2t+1 (->x1qO[t]); t<2 add l=512+t.
    QFilt f = load_qfilt(g0a, g0b, g1a, g1b);
    float4 mq0, mq1;
    {
        int l = 2 * tid;
        mq0 = quad_i(lo_s, 2 * l + 2, r1_s, i1_s, l + 1, f);
        mq1 = quad_i(lo_s, 2 * l + 4, r1_s, i1_s, l + 2, f);
        if (bnd) {
            int sA = s0 - 1 + l;
            if (sA < 0 || sA >= t4) mq0 = make_float4(0.f, 0.f, 0.f, 0.f);
            if (sA + 1 < 0 || sA + 1 >= t4) mq1 = make_float4(0.f, 0.f, 0.f, 0.f);
        }
        x1qE[tid] = mq0; x1qO[tid] = mq1;
        if (tid < 2) {
            int l2 = 512 + tid;
            float4 q = quad_i(lo_s, 2 * l2 + 2, r1_s, i1_s, l2 + 1, f);
            if (bnd) {
                int s = s0 - 1 + l2;
                if (s < 0 || s >= t4) q = make_float4(0.f, 0.f, 0.f, 0.f);
            }
            if (tid == 0) x1qE[256] = q; else x1qO[256] = q;
        }
    }
    __syncthreads();

    // phase B: w[d] = x1[n0 - 4 + 8*tid + d], d=0..15 (quads 2t..2t+3)
    float w[16];
    *reinterpret_cast<float4*>(&w[0])  = mq0;            // own, no LDS read
    *reinterpret_cast<float4*>(&w[4])  = mq1;
    *reinterpret_cast<float4*>(&w[8])  = x1qE[tid + 1];
    *reinterpret_cast<float4*>(&w[12]) = x1qO[tid + 1];

    float o[8];
#pragma unroll
    for (int p = 0; p < 8; ++p) {
        float acc = 0.f;
#pragma unroll
        for (int j = 0; j < 7; ++j)          // x1[n+3-j] -> w[p+7-j]
            acc = fmaf(g0r[j], w[p + 7 - j], acc);
#pragma unroll
        for (int j = 0; j < 5; ++j) {        // hi0[n+2-j] -> e = p+4-j
            int e = p + 4 - j;
            float v = (e & 1) ? iA[e >> 1] : rA[e >> 1];
            acc = fmaf(g1r[j], v, acc);
        }
        o[p] = acc;
    }
    float4* op = reinterpret_cast<float4*>(out + (size_t)row * T_ + n0) + 2 * tid;
    op[0] = make_float4(o[0], o[1], o[2], o[3]);
    op[1] = make_float4(o[4], o[5], o[6], o[7]);
}

extern "C" void kernel_launch(void* const* d_in, const int* in_sizes, int n_in,
                              void* d_out, int out_size, void* d_ws, size_t ws_size,
                              hipStream_t stream)
{
    const float* yl = (const float*)d_in[0];
    const float* yhr[8]; const float* yhi[8];
    for (int j = 0; j < 8; ++j) {
        yhr[j] = (const float*)d_in[1 + 2 * j];
        yhi[j] = (const float*)d_in[2 + 2 * j];
    }
    const float* g0o = (const float*)d_in[17];
    const float* g1o = (const float*)d_in[18];
    const float* g0a = (const float*)d_in[19];
    const float* g0b = (const float*)d_in[20];
    const float* g1a = (const float*)d_in[21];
    const float* g1b = (const float*)d_in[22];

    const int BC = 32 * 4;
    const int T_ = 262144;

    // Scratch: x2 (64 MiB) in ws. x6 (4.2 MiB) and x4 (16.8 MiB) carved from
    // d_out's tail — both fully consumed before final_lvl overwrites d_out.
    float* x2buf = (float*)d_ws;
    float* x4buf = (float*)((char*)d_out + ((size_t)64 << 20));
    float* x6buf = (float*)((char*)d_out + ((size_t)96 << 20));

    // K76: yl + yh7 + yh6 -> x6 (L = 8192)
    {
        dim3 grid(8192 / 1024, BC);
        pair_lvl<<<grid, BLOCK, 0, stream>>>(
            yl, yhr[7], yhi[7], yhr[6], yhi[6], x6buf,
            g0a, g0b, g1a, g1b, 8192);
    }
    // K54: x6 + yh5 + yh4 -> x4 (L = 32768)
    {
        dim3 grid(32768 / 1024, BC);
        pair_lvl<<<grid, BLOCK, 0, stream>>>(
            x6buf, yhr[5], yhi[5], yhr[4], yhi[4], x4buf,
            g0a, g0b, g1a, g1b, 32768);
    }
    // K32: x4 + yh3 + yh2 -> x2 (L = 131072)
    {
        dim3 grid(131072 / 1024, BC);
        pair_lvl<<<grid, BLOCK, 0, stream>>>(
            x4buf, yhr[3], yhi[3], yhr[2], yhi[2], x2buf,
            g0a, g0b, g1a, g1b, 131072);
    }
    // final: x2 + yh1 + yh0 -> out (FT = 2048 outputs/block, 8/thread)
    dim3 grid(T_ / FT, BC);
    final_lvl<<<grid, BLOCK, 0, stream>>>(
        x2buf, yhr[1], yhi[1], yhr[0], yhi[0], (float*)d_out,
        g0a, g0b, g1a, g1b, g0o, g1o, T_);
}

// Round 2
// 127.601 us; speedup vs baseline: 1.0494x; 1.0494x over previous
//
#include <hip/hip_runtime.h>

#define BLOCK 256
#define FT 1024           // output elements per block (final kernel) — R14: back to 1024

static __device__ __forceinline__ float ldz(const float* __restrict__ p, int i, int n) {
    return (i >= 0 && i < n) ? p[i] : 0.f;
}

// Quad-filter taps, reversed/deinterleaved, sqrt2 folded into the highpass set.
struct QFilt {
    float b0e[5], b0o[5], a0e[5], a0o[5];
    float b1e[5], b1o[5], a1e[5], a1o[5];
};

static __device__ __forceinline__ QFilt load_qfilt(
    const float* __restrict__ g0a, const float* __restrict__ g0b,
    const float* __restrict__ g1a, const float* __restrict__ g1b) {
    const float S2 = 1.4142135623730951f;
    QFilt f;
#pragma unroll
    for (int i = 0; i < 5; ++i) {
        f.b0e[i] = g0b[8 - 2 * i]; f.b0o[i] = g0b[9 - 2 * i];
        f.a0e[i] = g0a[8 - 2 * i]; f.a0o[i] = g0a[9 - 2 * i];
        f.b1e[i] = S2 * g1b[8 - 2 * i]; f.b1o[i] = S2 * g1b[9 - 2 * i];
        f.a1e[i] = S2 * g1a[8 - 2 * i]; f.a1o[i] = S2 * g1a[9 - 2 * i];
    }
    return f;
}

// Quad out[4s..4s+3], lo window consecutive in LDS starting at lobase
// (lo_s[lobase+g] = lo[2s-4+g], g=0..9); r/i stride-1 windows at ribase.
static __device__ __forceinline__ float4 quad_i(
    const float* __restrict__ lo_s, int lobase,
    const float* __restrict__ r_s, const float* __restrict__ i_s, int ribase,
    const QFilt& f) {
    float y0 = 0.f, y1 = 0.f, y2 = 0.f, y3 = 0.f;
#pragma unroll
    for (int i = 0; i < 5; ++i) {
        float ve = lo_s[lobase + 2 * i], vo = lo_s[lobase + 2 * i + 1];
        float vr = r_s[ribase + i], vi = i_s[ribase + i];
        y0 = fmaf(ve, f.b0e[i], y0); y2 = fmaf(ve, f.b0o[i], y2);
        y1 = fmaf(vo, f.a0e[i], y1); y3 = fmaf(vo, f.a0o[i], y3);
        y0 = fmaf(vr, f.b1e[i], y0); y2 = fmaf(vr, f.b1o[i], y2);
        y1 = fmaf(vi, f.a1e[i], y1); y3 = fmaf(vi, f.a1o[i], y3);
    }
    return make_float4(y0, y1, y2, y3);
}

// Quad with lo window DEINTERLEAVED: Ae[base+i]=lo[2s-4+2i], Ao[base+i]=lo[2s-3+2i].
static __device__ __forceinline__ float4 quad_d(
    const float* __restrict__ Ae, const float* __restrict__ Ao, int base,
    const float* __restrict__ r_s, const float* __restrict__ i_s, int ribase,
    const QFilt& f) {
    float y0 = 0.f, y1 = 0.f, y2 = 0.f, y3 = 0.f;
#pragma unroll
    for (int i = 0; i < 5; ++i) {
        float ve = Ae[base + i], vo = Ao[base + i];
        float vr = r_s[ribase + i], vi = i_s[ribase + i];
        y0 = fmaf(ve, f.b0e[i], y0); y2 = fmaf(ve, f.b0o[i], y2);
        y1 = fmaf(vo, f.a0e[i], y1); y3 = fmaf(vo, f.a0o[i], y3);
        y0 = fmaf(vr, f.b1e[i], y0); y2 = fmaf(vr, f.b1o[i], y2);
        y1 = fmaf(vi, f.a1e[i], y1); y3 = fmaf(vi, f.a1o[i], y3);
    }
    return make_float4(y0, y1, y2, y3);
}

// TWO fused coarse levels (R11 structure, unchanged — measured near floor).
__global__ void __launch_bounds__(BLOCK) pair_lvl(
    const float* __restrict__ up,
    const float* __restrict__ ru, const float* __restrict__ iu,
    const float* __restrict__ rl, const float* __restrict__ il,
    float* __restrict__ out,
    const float* __restrict__ g0a, const float* __restrict__ g0b,
    const float* __restrict__ g1a, const float* __restrict__ g1b,
    int L)
{
    __shared__ __align__(16) float upw[272], ruw[140], iuw[140], rlw[264], ilw[264];
    __shared__ __align__(16) float Ae[260], Ao[260];
    int tid = threadIdx.x, bx = blockIdx.x, row = blockIdx.y;
    int lup = L >> 2, lu8 = L >> 3, lql = L >> 2;
    const float* uprow = up + (size_t)row * lup;
    const float* rurow = ru + (size_t)row * lu8;
    const float* iurow = iu + (size_t)row * lu8;
    const float* rlrow = rl + (size_t)row * lql;
    const float* ilrow = il + (size_t)row * lql;
    bool bnd = (bx == 0) || (bx == (int)gridDim.x - 1);
    int S = bx << 8;
    int sAu = (S >> 1) - 1;
    int gu = S - 8;
    int gru = (S >> 1) - 4;
    int grl = S - 4;

    for (int i = tid; i < 270; i += BLOCK) {
        const float* src; float* dst; int k, gb, len;
        if (i < 68)       { src = uprow; dst = upw; k = i;       gb = gu + 4 * k;  len = lup; }
        else if (i < 103) { src = rurow; dst = ruw; k = i - 68;  gb = gru + 4 * k; len = lu8; }
        else if (i < 138) { src = iurow; dst = iuw; k = i - 103; gb = gru + 4 * k; len = lu8; }
        else if (i < 204) { src = rlrow; dst = rlw; k = i - 138; gb = grl + 4 * k; len = lql; }
        else              { src = ilrow; dst = ilw; k = i - 204; gb = grl + 4 * k; len = lql; }
        float4 v;
        if (!bnd) v = *reinterpret_cast<const float4*>(src + gb);
        else { v.x = ldz(src, gb, len); v.y = ldz(src, gb + 1, len);
               v.z = ldz(src, gb + 2, len); v.w = ldz(src, gb + 3, len); }
        *reinterpret_cast<float4*>(dst + 4 * k) = v;
    }
    __syncthreads();

    QFilt f = load_qfilt(g0a, g0b, g1a, g1b);
    if (tid < 130) {
        float4 q = quad_i(upw, 2 * tid + 2, ruw, iuw, tid + 1, f);
        if (bnd) {
            int sp = sAu + tid;
            if (sp < 0 || sp >= lu8) q = make_float4(0.f, 0.f, 0.f, 0.f);
        }
        Ae[2 * tid] = q.x; Ae[2 * tid + 1] = q.z;
        Ao[2 * tid] = q.y; Ao[2 * tid + 1] = q.w;
    }
    __syncthreads();

    float4 res = quad_d(Ae, Ao, tid, rlw, ilw, tid + 2, f);
    reinterpret_cast<float4*>(out + (size_t)row * L)[S + tid] = res;
}

// R14: FOUR fused levels: x4 + yh3 + yh2 + yh1 + yh0 -> out.
// Rationale: R13 showed final_lvl time tracks total vector volume, not
// per-block overhead (FT 1024->2048 was exactly neutral). So eliminate the
// K32 kernel + the 64 MiB x2 round-trip by computing x3 (phase A), x2
// (phase B) in-block before the proven x1 (phase C) + epilogue (phase D).
// Halo math: per 1024 outputs need 258 x1-quads <- 132 x2-quads <- 69
// x3-quads <- 148 x4 floats. All staged windows float4-aligned.
__global__ void __launch_bounds__(BLOCK) final4_lvl(
    const float* __restrict__ x4,                                 // T/8 per row
    const float* __restrict__ r3, const float* __restrict__ i3,   // T/16 per row
    const float* __restrict__ r2, const float* __restrict__ i2,   // T/8 per row
    const float* __restrict__ r1, const float* __restrict__ i1,   // T/4 per row
    const float* __restrict__ r0, const float* __restrict__ i0,   // T/2 per row
    float* __restrict__ out,                                      // T per row
    const float* __restrict__ g0a, const float* __restrict__ g0b,
    const float* __restrict__ g1a, const float* __restrict__ g1b,
    const float* __restrict__ g0o, const float* __restrict__ g1o,
    int T_)
{
    const float S2 = 1.4142135623730951f;
    __shared__ __align__(16) float x4w[152], r3w[80], i3w[80];
    __shared__ __align__(16) float r2w[144], i2w[144];
    __shared__ __align__(16) float r1w[264], i1w[264];
    __shared__ __align__(16) float x3s[280], x2s[528];
    __shared__ __align__(16) float4 x1q[258];

    int row = blockIdx.y, tid = threadIdx.x;
    int n0 = blockIdx.x * FT;
    int t2 = T_ >> 1, t4 = T_ >> 2, t8 = T_ >> 3, t16 = T_ >> 4;
    int s0 = n0 >> 2, u0 = n0 >> 3, v0 = n0 >> 4, h0 = n0 >> 1;
    const float* x4row = x4 + (size_t)row * t8;
    const float* r3row = r3 + (size_t)row * t16;
    const float* i3row = i3 + (size_t)row * t16;
    const float* r2row = r2 + (size_t)row * t8;
    const float* i2row = i2 + (size_t)row * t8;
    const float* r1row = r1 + (size_t)row * t4;
    const float* i1row = i1 + (size_t)row * t4;
    const float* r0row = r0 + (size_t)row * t2;
    const float* i0row = i0 + (size_t)row * t2;
    bool bnd = (blockIdx.x == 0) || ((int)blockIdx.x == (int)gridDim.x - 1);

    // ---- hoisted epilogue loads: rA[e] = r0[h0 + 2*tid - 1 + e], e=0..3 ----
    // (issued at entry so HBM latency overlaps stage + phases A..C)
    float rA[4], iA[4];
    {
        int u0e = h0 + 2 * tid - 1;
        if (!bnd) {
            float4 va = *reinterpret_cast<const float4*>(r0row + u0e);
            float4 vb = *reinterpret_cast<const float4*>(i0row + u0e);
            rA[0] = va.x; rA[1] = va.y; rA[2] = va.z; rA[3] = va.w;
            iA[0] = vb.x; iA[1] = vb.y; iA[2] = vb.z; iA[3] = vb.w;
        } else {
#pragma unroll
            for (int e = 0; e < 4; ++e) {
                rA[e] = ldz(r0row, u0e + e, t2);
                iA[e] = ldz(i0row, u0e + e, t2);
            }
        }
    }
    float g0r[7], g1r[5];
#pragma unroll
    for (int j = 0; j < 7; ++j) g0r[j] = g0o[j];
#pragma unroll
    for (int j = 0; j < 5; ++j) g1r[j] = S2 * g1o[j];

    // ---- stage all quad-tree inputs (float4 granulated; 277 vec4 loads) ----
    // x4w[g]=x4[2*v0-8+g] g<148 | r3w/i3w[g]=yh3[v0-4+g] g<76
    // r2w/i2w[g]=yh2[u0-4+g] g<140 | r1w/i1w[g]=yh1[s0-4+g] g<264
    for (int i = tid; i < 277; i += BLOCK) {
        const float* src; float* dst; int k, gb, len;
        if (i < 37)       { src = x4row; dst = x4w; k = i;       gb = 2 * v0 - 8 + 4 * k; len = t8; }
        else if (i < 56)  { src = r3row; dst = r3w; k = i - 37;  gb = v0 - 4 + 4 * k;     len = t16; }
        else if (i < 75)  { src = i3row; dst = i3w; k = i - 56;  gb = v0 - 4 + 4 * k;     len = t16; }
        else if (i < 110) { src = r2row; dst = r2w; k = i - 75;  gb = u0 - 4 + 4 * k;     len = t8; }
        else if (i < 145) { src = i2row; dst = i2w; k = i - 110; gb = u0 - 4 + 4 * k;     len = t8; }
        else if (i < 211) { src = r1row; dst = r1w; k = i - 145; gb = s0 - 4 + 4 * k;     len = t4; }
        else              { src = i1row; dst = i1w; k = i - 211; gb = s0 - 4 + 4 * k;     len = t4; }
        float4 v;
        if (!bnd) v = *reinterpret_cast<const float4*>(src + gb);
        else { v.x = ldz(src, gb, len); v.y = ldz(src, gb + 1, len);
               v.z = ldz(src, gb + 2, len); v.w = ldz(src, gb + 3, len); }
        *reinterpret_cast<float4*>(dst + 4 * k) = v;
    }
    __syncthreads();

    QFilt f = load_qfilt(g0a, g0b, g1a, g1b);

    // ---- phase A: 69 x3-quads. quad v = v0-2+k covers x3[4v..4v+3].
    // x4 window x4[2v-4..2v+5] -> x4w base 2k; yh3 window [v-2..v+2] -> base k.
    if (tid < 69) {
        int k = tid;
        float4 q = quad_i(x4w, 2 * k, r3w, i3w, k, f);
        if (bnd) {
            int v = v0 - 2 + k;
            if (v < 0 || v >= t16) q = make_float4(0.f, 0.f, 0.f, 0.f);
        }
        reinterpret_cast<float4*>(x3s)[k] = q;
    }
    __syncthreads();

    // ---- phase B: 132 x2-quads. quad u = u0-2+k covers x2[4u..4u+3].
    // x3 window x3[2u-4..2u+5] -> x3s base 2k (x3s[g]=x3[4*v0-8+g]);
    // yh2 window [u-2..u+2] -> r2w base k.
    if (tid < 132) {
        int k = tid;
        float4 q = quad_i(x3s, 2 * k, r2w, i2w, k, f);
        if (bnd) {
            int u = u0 - 2 + k;
            if (u < 0 || u >= t8) q = make_float4(0.f, 0.f, 0.f, 0.f);
        }
        reinterpret_cast<float4*>(x2s)[k] = q;
    }
    __syncthreads();

    // ---- phase C: 258 x1-quads (proven R12 structure). quad l -> s = s0-1+l.
    // x2s[g]=x2[2*s0-8+g] -> base 2l+2; yh1 window -> base l+1.
    float4 myq;
    {
        int l = tid;
        float4 q = quad_i(x2s, 2 * l + 2, r1w, i1w, l + 1, f);
        if (bnd) {
            int s = s0 - 1 + l;
            if (s < 0 || s >= t4) q = make_float4(0.f, 0.f, 0.f, 0.f);
        }
        myq = q;
        x1q[l] = q;
        if (tid < 2) {
            int l2 = 256 + tid;
            q = quad_i(x2s, 2 * l2 + 2, r1w, i1w, l2 + 1, f);
            if (bnd) {
                int s = s0 - 1 + l2;
                if (s < 0 || s >= t4) q = make_float4(0.f, 0.f, 0.f, 0.f);
            }
            x1q[l2] = q;
        }
    }
    __syncthreads();

    // ---- phase D: epilogue. w[d] = x1[n0-4+4*tid+d]; own quad in regs.
    float w[12];
    *reinterpret_cast<float4*>(&w[0]) = myq;
    *reinterpret_cast<float4*>(&w[4]) = x1q[tid + 1];
    *reinterpret_cast<float4*>(&w[8]) = x1q[tid + 2];

    float o[4];
#pragma unroll
    for (int p = 0; p < 4; ++p) {
        float acc = 0.f;
#pragma unroll
        for (int j = 0; j < 7; ++j)          // x1[n+3-j] -> w[p+7-j]
            acc = fmaf(g0r[j], w[p + 7 - j], acc);
#pragma unroll
        for (int j = 0; j < 5; ++j) {        // hi0[n+2-j] -> e = p+4-j
            int e = p + 4 - j;
            float v = (e & 1) ? iA[e >> 1] : rA[e >> 1];
            acc = fmaf(g1r[j], v, acc);
        }
        o[p] = acc;
    }
    reinterpret_cast<float4*>(out + (size_t)row * T_)[s0 + tid] =
        make_float4(o[0], o[1], o[2], o[3]);
}

extern "C" void kernel_launch(void* const* d_in, const int* in_sizes, int n_in,
                              void* d_out, int out_size, void* d_ws, size_t ws_size,
                              hipStream_t stream)
{
    const float* yl = (const float*)d_in[0];
    const float* yhr[8]; const float* yhi[8];
    for (int j = 0; j < 8; ++j) {
        yhr[j] = (const float*)d_in[1 + 2 * j];
        yhi[j] = (const float*)d_in[2 + 2 * j];
    }
    const float* g0o = (const float*)d_in[17];
    const float* g1o = (const float*)d_in[18];
    const float* g0a = (const float*)d_in[19];
    const float* g0b = (const float*)d_in[20];
    const float* g1a = (const float*)d_in[21];
    const float* g1b = (const float*)d_in[22];

    const int BC = 32 * 4;
    const int T_ = 262144;

    // R14 scratch: final4 reads x4 while writing the FULL d_out, so x4/x6
    // must NOT alias d_out anymore. x2 is gone (fused), freeing ws:
    //   x4 (16.8 MiB) at ws+0, x6 (4.2 MiB) at ws+32MiB.
    float* x4buf = (float*)d_ws;
    float* x6buf = (float*)((char*)d_ws + ((size_t)32 << 20));

    // K76: yl + yh7 + yh6 -> x6 (L = 8192)
    {
        dim3 grid(8192 / 1024, BC);
        pair_lvl<<<grid, BLOCK, 0, stream>>>(
            yl, yhr[7], yhi[7], yhr[6], yhi[6], x6buf,
            g0a, g0b, g1a, g1b, 8192);
    }
    // K54: x6 + yh5 + yh4 -> x4 (L = 32768)
    {
        dim3 grid(32768 / 1024, BC);
        pair_lvl<<<grid, BLOCK, 0, stream>>>(
            x6buf, yhr[5], yhi[5], yhr[4], yhi[4], x4buf,
            g0a, g0b, g1a, g1b, 32768);
    }
    // final4: x4 + yh3 + yh2 + yh1 + yh0 -> out (4 levels fused)
    dim3 grid(T_ / FT, BC);
    final4_lvl<<<grid, BLOCK, 0, stream>>>(
        x4buf, yhr[3], yhi[3], yhr[2], yhi[2], yhr[1], yhi[1],
        yhr[0], yhi[0], (float*)d_out,
        g0a, g0b, g1a, g1b, g0o, g1o, T_);
}